// Round 1
// baseline (647.836 us; speedup 1.0000x reference)
//
#include <hip/hip_runtime.h>

// GlobalContrastiveLoss, B=131072, D=512, N=1, fp32 in, fp32 scalar out.
// N==1 makes the cosine/argmax branch dead; loss_b = log1p(exp((dn-dp)/50)).
// Memory-bound: 805 MB read -> ~130 us floor at 6.3 TB/s.

#define BLOCK 256
#define WAVES_PER_BLOCK (BLOCK / 64)
#define NBLOCKS 2048
#define DCOLS 512

__global__ __launch_bounds__(BLOCK) void gcl_partial_kernel(
    const float* __restrict__ img,
    const float* __restrict__ pos,
    const float* __restrict__ neg,
    float* __restrict__ partials,
    int B)
{
    const int lane  = threadIdx.x & 63;
    const int wave  = threadIdx.x >> 6;
    const int gwave = blockIdx.x * WAVES_PER_BLOCK + wave;
    const int nwaves = gridDim.x * WAVES_PER_BLOCK;

    float acc = 0.0f;

    for (int row = gwave; row < B; row += nwaves) {
        const size_t base = (size_t)row * DCOLS;
        const float4* i4 = (const float4*)(img + base);
        const float4* p4 = (const float4*)(pos + base);
        const float4* n4 = (const float4*)(neg + base);

        // 512 floats/row = 128 float4; 64 lanes x 2 iterations, coalesced.
        float4 a0 = i4[lane];
        float4 a1 = i4[lane + 64];
        float4 b0 = p4[lane];
        float4 b1 = p4[lane + 64];
        float4 c0 = n4[lane];
        float4 c1 = n4[lane + 64];

        float dp = a0.x * b0.x + a0.y * b0.y + a0.z * b0.z + a0.w * b0.w
                 + a1.x * b1.x + a1.y * b1.y + a1.z * b1.z + a1.w * b1.w;
        float dn = a0.x * c0.x + a0.y * c0.y + a0.z * c0.z + a0.w * c0.w
                 + a1.x * c1.x + a1.y * c1.y + a1.z * c1.z + a1.w * c1.w;

        // Wave-wide butterfly reduction (64 lanes).
        #pragma unroll
        for (int off = 32; off >= 1; off >>= 1) {
            dp += __shfl_xor(dp, off, 64);
            dn += __shfl_xor(dn, off, 64);
        }

        if (lane == 0) {
            // -log(ep/(ep+en)) = log1p(exp((dn-dp)/50))
            acc += log1pf(__expf((dn - dp) * 0.02f));
        }
    }

    __shared__ float sacc[WAVES_PER_BLOCK];
    if (lane == 0) sacc[wave] = acc;
    __syncthreads();

    if (threadIdx.x == 0) {
        float s = 0.0f;
        #pragma unroll
        for (int w = 0; w < WAVES_PER_BLOCK; ++w) s += sacc[w];
        partials[blockIdx.x] = s;
    }
}

__global__ __launch_bounds__(256) void gcl_final_kernel(
    const float* __restrict__ partials, int n, float* __restrict__ out, float invB)
{
    __shared__ float s[256];
    float a = 0.0f;
    for (int i = threadIdx.x; i < n; i += 256) a += partials[i];
    s[threadIdx.x] = a;
    __syncthreads();
    #pragma unroll
    for (int stride = 128; stride > 0; stride >>= 1) {
        if (threadIdx.x < stride) s[threadIdx.x] += s[threadIdx.x + stride];
        __syncthreads();
    }
    if (threadIdx.x == 0) out[0] = s[0] * invB;
}

extern "C" void kernel_launch(void* const* d_in, const int* in_sizes, int n_in,
                              void* d_out, int out_size, void* d_ws, size_t ws_size,
                              hipStream_t stream) {
    const float* img = (const float*)d_in[0];
    const float* pos = (const float*)d_in[1];
    const float* neg = (const float*)d_in[2];
    float* out = (float*)d_out;
    float* partials = (float*)d_ws;

    const int B = in_sizes[0] / DCOLS;  // N == 1

    int nblocks = NBLOCKS;
    if (ws_size < (size_t)nblocks * sizeof(float)) {
        nblocks = (int)(ws_size / sizeof(float));  // safety; ws is ample in practice
        if (nblocks < 1) nblocks = 1;
    }

    gcl_partial_kernel<<<nblocks, BLOCK, 0, stream>>>(img, pos, neg, partials, B);
    gcl_final_kernel<<<1, 256, 0, stream>>>(partials, nblocks, out, 1.0f / (float)B);
}